// Round 5
// baseline (422.658 us; speedup 1.0000x reference)
//
#include <hip/hip_runtime.h>
#include <math.h>

#define GXD 128
#define GYD 128
#define GZD 32
#define DD  64
#define GCELLS (GXD * GYD * GZD)   // 524288

#define MINX (-20.0f)
#define MINY (-20.0f)
#define MINZ (-2.0f)
#define VOXX (0.3125f)
#define VOXY (0.3125f)
#define VOXZ (0.25f)
#define ELL  (0.5f)
#define EPSV (1e-6f)
#define PIF  (3.14159265358979323846f)

// Column weights: for the 9 (ox,oy) columns, w0 = kval at oz=0, w1 = kval at
// |oz|=1. Corners (|ox|=|oy|=1) have w1 == 0 (d >= ELL) — skipped at compile
// time in the kernel. Column index c = (ox+1)*3 + (oy+1).
struct KvCols { float w0[9]; float w1[9]; };

// ---------------------------------------------------------------------------
__device__ __forceinline__ float kval_of(int o) {   // fallback path only
    int ox = o / 9 - 1;
    int oy = (o / 3) % 3 - 1;
    int oz = o % 3 - 1;
    float dx = ox * VOXX, dy = oy * VOXY, dz = oz * VOXZ;
    float d = sqrtf(dx * dx + dy * dy + dz * dz);
    float ang = 2.0f * PIF * d / ELL;
    float v = (1.0f / 3.0f) * (2.0f + cosf(ang)) * (1.0f - d / ELL)
            + (1.0f / (2.0f * PIF)) * sinf(ang);
    v = (d >= ELL) ? 0.0f : v;
    return fminf(fmaxf(v, 0.0f), 1.0f);
}

__device__ __forceinline__ int base_cell(const float* __restrict__ row,
                                         int* cx, int* cy, int* cz) {
    float x = row[0], y = row[1], z = row[2];
    int gx = (int)floorf((x - MINX) / VOXX);
    int gy = (int)floorf((y - MINY) / VOXY);
    int gz = (int)floorf((z - MINZ) / VOXZ);
    gx = min(max(gx, 0), GXD - 1);
    gy = min(max(gy, 0), GYD - 1);
    gz = min(max(gz, 0), GZD - 1);
    *cx = gx; *cy = gy; *cz = gz;
    return (gx * GYD + gy) * GZD + gz;
}

// ===========================================================================
// FAST PATH — workspace (floats):
//   M0 : [0, GCELLS+64)                    cell counts; [GCELLS..] zero sentinel
//   MM : [GCELLS+64, +GCELLS*128+128)      interleaved (m1,m2) pairs per
//                                          (cell,feature); row at element
//                                          GCELLS*128 is the zero sentinel row
// ===========================================================================

// Pass 1: zero the MM rows of touched base cells (races benign: all write 0)
__global__ void lbki_zero_rows(const float* __restrict__ pc,
                               float2* __restrict__ MM2,
                               int npts) {
    int lane = threadIdx.x & 63;
    int wave = threadIdx.x >> 6;
    int p = blockIdx.x * (blockDim.x >> 6) + wave;
    if (p >= npts) return;
    int cx, cy, cz;
    int g = base_cell(pc + (size_t)p * 67, &cx, &cy, &cz);
    MM2[(size_t)g * DD + lane] = make_float2(0.0f, 0.0f);
}

// Pass 2: scatter per-point raw moments into the BASE cell only.
__global__ void lbki_build(const float* __restrict__ pc,
                           float* __restrict__ M0,
                           float* __restrict__ MM,
                           int npts) {
    int lane = threadIdx.x & 63;
    int wave = threadIdx.x >> 6;
    int p = blockIdx.x * (blockDim.x >> 6) + wave;
    if (p >= npts) return;
    const float* row = pc + (size_t)p * 67;
    int cx, cy, cz;
    int g = base_cell(row, &cx, &cy, &cz);
    float f = row[3 + lane];
    size_t e = ((size_t)g * DD + lane) * 2;
    atomicAdd(&MM[e],     f);
    atomicAdd(&MM[e + 1], f * f);
    if (lane == 0) atomicAdd(&M0[g], 1.0f);
}

// Pass 3: z-column stencil fused with finalize.
// One wave per (x,y) column; lane = feature; z fully unrolled with rolling
// register windows. Gating by cnt!=0 via sentinel cndmask (straight-line).
__global__ __launch_bounds__(256)
void lbki_stencil_col(const float* __restrict__ M0,
                      const float* __restrict__ MM,
                      const float* __restrict__ mean_map,
                      const float* __restrict__ var_map,
                      const float* __restrict__ conf_map,
                      float* __restrict__ out_mean,
                      float* __restrict__ out_var,
                      float* __restrict__ out_conf,
                      KvCols ka) {
    const int lane = threadIdx.x & 63;
    const int wave = threadIdx.x >> 6;

    // bijective XCD swizzle: 4096 blocks, % 8 == 0; each XCD sweeps a
    // contiguous 16-x-plane slab (y fastest) -> stencil reuse stays in its L2.
    unsigned b = blockIdx.x;
    unsigned chunk = gridDim.x >> 3;
    unsigned swz = (b & 7u) * chunk + (b >> 3);
    const int col = (int)(swz * 4u + (unsigned)wave);   // [0, 16384)
    const int cx = col >> 7;
    const int cy = col & (GYD - 1);

    // per-column bases (computed ONCE per 32 cells)
    const unsigned sentM = (unsigned)GCELLS * (DD * 2u) + (unsigned)lane * 2u;
    unsigned off0[9];   // M0 element index of plane z=0 (or sentinel)
    unsigned offM[9];   // MM float-element index of (z=0, lane) pair (or sentinel)
    #pragma unroll
    for (int c = 0; c < 9; ++c) {
        int ox = c / 3 - 1, oy = c % 3 - 1;
        int nx = cx + ox, ny = cy + oy;
        bool v = ((unsigned)nx < (unsigned)GXD) && ((unsigned)ny < (unsigned)GYD);
        unsigned colcell = (unsigned)((nx * GYD + ny) * GZD);
        off0[c] = v ? colcell : (unsigned)GCELLS;
        offM[c] = v ? colcell * (DD * 2u) + (unsigned)lane * 2u : sentM;
    }

    const unsigned gbase = (unsigned)col * (unsigned)GZD;    // cell idx of z=0
    const unsigned rbase = gbase * DD + (unsigned)lane;      // row elem of z=0

    // rolling windows (all indices compile-time after full unroll)
    float cnt[9][2];
    float m1w[9][4], m2w[9][4];
    float q0[4], q1[4];
    float mw[3], vw[3], cw[3];

    #pragma unroll
    for (int c = 0; c < 9; ++c) { m1w[c][3] = 0.0f; m2w[c][3] = 0.0f; }
    q1[3] = 0.0f;   // plane -1
    q0[3] = 0.0f;

    // ---- prologue: M0 planes 0,1 ----
    #pragma unroll
    for (int zp = 0; zp < 2; ++zp)
        #pragma unroll
        for (int c = 0; c < 9; ++c)
            cnt[c][zp & 1] = M0[off0[c] + (unsigned)zp];

    // ---- prologue: gate planes 0,1 -> q's + issue MM loads ----
    #pragma unroll
    for (int zp = 0; zp < 2; ++zp) {
        float a0 = 0.0f, a1 = 0.0f;
        #pragma unroll
        for (int c = 0; c < 9; ++c) {
            float cv = cnt[c][zp & 1];
            a0 += ka.w0[c] * cv;
            if (c == 1 || c == 3 || c == 4 || c == 5 || c == 7)
                a1 += ka.w1[c] * cv;
            unsigned mi = (cv != 0.0f) ? (offM[c] + (unsigned)(zp * DD * 2))
                                       : sentM;
            const float2 mm = *(const float2*)(MM + mi);
            m1w[c][zp & 3] = mm.x;
            m2w[c][zp & 3] = mm.y;
        }
        q0[zp & 3] = a0;
        q1[zp & 3] = a1;
    }

    // ---- prologue: M0 plane 2 (slot 0; plane 0 already consumed) ----
    #pragma unroll
    for (int c = 0; c < 9; ++c)
        cnt[c][0] = M0[off0[c] + 2u];

    // ---- prologue: mean/var/conf planes 0,1 ----
    #pragma unroll
    for (int zp = 0; zp < 2; ++zp) {
        mw[zp % 3] = mean_map[rbase + (unsigned)(zp * DD)];
        vw[zp % 3] = var_map [rbase + (unsigned)(zp * DD)];
        cw[zp % 3] = conf_map[gbase + (unsigned)zp];
    }

    // ---- main loop: fully unrolled z march ----
    #pragma unroll
    for (int z = 0; z < GZD; ++z) {
        // A: issue M0 plane z+3
        if (z + 3 < GZD) {
            #pragma unroll
            for (int c = 0; c < 9; ++c)
                cnt[c][(z + 3) & 1] = M0[off0[c] + (unsigned)(z + 3)];
        } else {
            #pragma unroll
            for (int c = 0; c < 9; ++c) cnt[c][(z + 3) & 1] = 0.0f;
        }

        // B: gate plane z+2 (cnt issued at step z-1) -> q's + issue MM loads
        {
            const int zp = z + 2;
            float a0 = 0.0f, a1 = 0.0f;
            if (zp < GZD) {
                #pragma unroll
                for (int c = 0; c < 9; ++c) {
                    float cv = cnt[c][zp & 1];
                    a0 += ka.w0[c] * cv;
                    if (c == 1 || c == 3 || c == 4 || c == 5 || c == 7)
                        a1 += ka.w1[c] * cv;
                    unsigned mi = (cv != 0.0f) ? (offM[c] + (unsigned)(zp * DD * 2))
                                               : sentM;
                    const float2 mm = *(const float2*)(MM + mi);
                    m1w[c][zp & 3] = mm.x;
                    m2w[c][zp & 3] = mm.y;
                }
            } else {
                #pragma unroll
                for (int c = 0; c < 9; ++c) {
                    m1w[c][zp & 3] = 0.0f;
                    m2w[c][zp & 3] = 0.0f;
                }
            }
            q0[zp & 3] = a0;
            q1[zp & 3] = a1;
        }

        // C: issue mean/var/conf plane z+2
        if (z + 2 < GZD) {
            mw[(z + 2) % 3] = mean_map[rbase + (unsigned)((z + 2) * DD)];
            vw[(z + 2) % 3] = var_map [rbase + (unsigned)((z + 2) * DD)];
            cw[(z + 2) % 3] = conf_map[gbase + (unsigned)(z + 2)];
        }

        // D: compute cell z from windows (planes z-1, z, z+1)
        float acc_k = q1[(z + 3) & 3] + q0[z & 3] + q1[(z + 1) & 3];
        float acc_y = 0.0f, acc_s = 0.0f;
        #pragma unroll
        for (int c = 0; c < 9; ++c) {
            acc_y += ka.w0[c] * m1w[c][z & 3];
            acc_s += ka.w0[c] * m2w[c][z & 3];
            if (c == 1 || c == 3 || c == 4 || c == 5 || c == 7) {
                acc_y += ka.w1[c] * (m1w[c][(z + 3) & 3] + m1w[c][(z + 1) & 3]);
                acc_s += ka.w1[c] * (m2w[c][(z + 3) & 3] + m2w[c][(z + 1) & 3]);
            }
        }

        float conf = cw[z % 3];
        float mean = mw[z % 3];
        float var  = vw[z % 3];
        float kb    = acc_k;
        float ybar  = acc_y / (kb + EPSV);
        float Sbar  = acc_s - 2.0f * ybar * acc_y + ybar * ybar * kb;
        float denom = conf + kb + EPSV;
        float dm    = ybar - mean;
        float scal  = conf * kb / denom;

        unsigned oidx = rbase + (unsigned)(z * DD);
        out_mean[oidx] = (conf * mean + kb * ybar) / denom;
        out_var[oidx]  = var + Sbar + scal * dm * dm;
        if (lane == 0) out_conf[gbase + (unsigned)z] = conf + kb;
    }
}

// ===========================================================================
// FALLBACK PATH (round-1 kernels, used only if workspace is too small)
// ===========================================================================
__global__ void lbki_accum(const float* __restrict__ pc,
                           float* __restrict__ y_sum,
                           float* __restrict__ sq_sum,
                           float* __restrict__ k_bar,
                           int npts) {
    __shared__ float kval_s[27];
    if (threadIdx.x < 27) kval_s[threadIdx.x] = kval_of(threadIdx.x);
    __syncthreads();

    int lane = threadIdx.x & 63;
    int wave = threadIdx.x >> 6;
    int p = blockIdx.x * (blockDim.x >> 6) + wave;
    if (p >= npts) return;

    const float* row = pc + (size_t)p * 67;
    int gx, gy, gz;
    base_cell(row, &gx, &gy, &gz);
    float f = row[3 + lane];
    float ff = f * f;

    #pragma unroll
    for (int o = 0; o < 27; ++o) {
        float kv = kval_s[o];
        if (kv <= 0.0f) continue;
        int nx = gx + (o / 9) - 1;
        int ny = gy + ((o / 3) % 3) - 1;
        int nz = gz + (o % 3) - 1;
        if ((unsigned)nx >= (unsigned)GXD) continue;
        if ((unsigned)ny >= (unsigned)GYD) continue;
        if ((unsigned)nz >= (unsigned)GZD) continue;
        size_t g = ((size_t)nx * GYD + ny) * GZD + nz;
        atomicAdd(&y_sum[g * DD + lane], kv * f);
        atomicAdd(&sq_sum[g * DD + lane], kv * ff);
        if (lane == 0) atomicAdd(&k_bar[g], kv);
    }
}

__global__ void lbki_finalize(const float* __restrict__ mean_map,
                              const float* __restrict__ var_map,
                              const float* __restrict__ conf_map,
                              float* __restrict__ out_mean,
                              float* __restrict__ out_var,
                              float* __restrict__ out_conf) {
    int lane = threadIdx.x & 63;
    int wave = threadIdx.x >> 6;
    int g = blockIdx.x * (blockDim.x >> 6) + wave;
    if (g >= GCELLS) return;

    float kb   = out_conf[g];
    float conf = conf_map[g];

    size_t idx = (size_t)g * DD + lane;
    float ys   = out_mean[idx];
    float sq   = out_var[idx];
    float mean = mean_map[idx];
    float var  = var_map[idx];

    float ybar  = ys / (kb + EPSV);
    float Sbar  = sq - 2.0f * ybar * ys + ybar * ybar * kb;
    float denom = conf + kb + EPSV;
    float dm    = ybar - mean;
    float scal  = conf * kb / denom;

    out_mean[idx] = (conf * mean + kb * ybar) / denom;
    out_var[idx]  = var + Sbar + scal * dm * dm;
    if (lane == 0) out_conf[g] = conf + kb;
}

// ===========================================================================
extern "C" void kernel_launch(void* const* d_in, const int* in_sizes, int n_in,
                              void* d_out, int out_size, void* d_ws, size_t ws_size,
                              hipStream_t stream) {
    const float* mean_map = (const float*)d_in[0];
    const float* var_map  = (const float*)d_in[1];
    const float* conf_map = (const float*)d_in[2];
    const float* pc       = (const float*)d_in[3];
    int npts = in_sizes[3] / 67;

    float* out      = (float*)d_out;
    float* out_mean = out;
    float* out_var  = out + (size_t)GCELLS * DD;
    float* out_conf = out + (size_t)2 * GCELLS * DD;

    const size_t M0_ELEMS = (size_t)GCELLS + 64;             // + sentinel
    const size_t MM_ELEMS = (size_t)GCELLS * DD * 2 + 128;   // + sentinel row
    const size_t WS_NEEDED = (M0_ELEMS + MM_ELEMS) * sizeof(float);

    if (ws_size >= WS_NEEDED) {
        float* M0 = (float*)d_ws;
        float* MM = M0 + M0_ELEMS;

        // zero M0 (+ sentinel) and the MM sentinel row
        hipMemsetAsync(M0, 0, M0_ELEMS * sizeof(float), stream);
        hipMemsetAsync(MM + (size_t)GCELLS * DD * 2, 0, 128 * sizeof(float), stream);

        int wpb = 4;
        int pblocks = (npts + wpb - 1) / wpb;
        lbki_zero_rows<<<pblocks, 256, 0, stream>>>(pc, (float2*)MM, npts);
        lbki_build<<<pblocks, 256, 0, stream>>>(pc, M0, MM, npts);

        // host-side column weights (double precision, cast to f32)
        KvCols ka;
        for (int c = 0; c < 9; ++c) {
            int ox = c / 3 - 1, oy = c % 3 - 1;
            for (int k = 0; k < 2; ++k) {   // k = |oz|
                double dx = ox * (double)VOXX;
                double dy = oy * (double)VOXY;
                double dz = k  * (double)VOXZ;
                double d  = sqrt(dx * dx + dy * dy + dz * dz);
                double ang = 2.0 * (double)PIF * d / (double)ELL;
                double v = (1.0 / 3.0) * (2.0 + cos(ang)) * (1.0 - d / (double)ELL)
                         + (1.0 / (2.0 * (double)PIF)) * sin(ang);
                if (d >= (double)ELL) v = 0.0;
                v = v < 0.0 ? 0.0 : (v > 1.0 ? 1.0 : v);
                if (k == 0) ka.w0[c] = (float)v; else ka.w1[c] = (float)v;
            }
        }

        int sblocks = (GXD * GYD) / 4;   // 4096 blocks, % 8 == 0
        lbki_stencil_col<<<sblocks, 256, 0, stream>>>(M0, MM,
                                                      mean_map, var_map, conf_map,
                                                      out_mean, out_var, out_conf,
                                                      ka);
    } else {
        hipMemsetAsync(d_out, 0, (size_t)out_size * sizeof(float), stream);
        int wpb = 4;
        int blocks = (npts + wpb - 1) / wpb;
        lbki_accum<<<blocks, 256, 0, stream>>>(pc, out_mean, out_var, out_conf, npts);
        int fblocks = GCELLS / 4;
        lbki_finalize<<<fblocks, 256, 0, stream>>>(mean_map, var_map, conf_map,
                                                   out_mean, out_var, out_conf);
    }
}

// Round 6
// 399.900 us; speedup vs baseline: 1.0569x; 1.0569x over previous
//
#include <hip/hip_runtime.h>
#include <math.h>

#define GXD 128
#define GYD 128
#define GZD 32
#define DD  64
#define GCELLS (GXD * GYD * GZD)   // 524288

#define MINX (-20.0f)
#define MINY (-20.0f)
#define MINZ (-2.0f)
#define VOXX (0.3125f)
#define VOXY (0.3125f)
#define VOXZ (0.25f)
#define ELL  (0.5f)
#define EPSV (1e-6f)
#define PIF  (3.14159265358979323846f)

// Column weights: for the 9 (ox,oy) columns, w0 = kval at oz=0, w1 = kval at
// |oz|=1. Corners (|ox|=|oy|=1) have w1 == 0 (d >= ELL) — skipped at compile
// time. Column index c = (ox+1)*3 + (oy+1).
struct KvCols { float w0[9]; float w1[9]; };

// plus-shaped columns (|ox|+|oy| <= 1) that have nonzero w1
#define IS_PLUS(c) ((c) == 1 || (c) == 3 || (c) == 4 || (c) == 5 || (c) == 7)

// ---------------------------------------------------------------------------
__device__ __forceinline__ float kval_of(int o) {   // fallback path only
    int ox = o / 9 - 1;
    int oy = (o / 3) % 3 - 1;
    int oz = o % 3 - 1;
    float dx = ox * VOXX, dy = oy * VOXY, dz = oz * VOXZ;
    float d = sqrtf(dx * dx + dy * dy + dz * dz);
    float ang = 2.0f * PIF * d / ELL;
    float v = (1.0f / 3.0f) * (2.0f + cosf(ang)) * (1.0f - d / ELL)
            + (1.0f / (2.0f * PIF)) * sinf(ang);
    v = (d >= ELL) ? 0.0f : v;
    return fminf(fmaxf(v, 0.0f), 1.0f);
}

__device__ __forceinline__ int base_cell(const float* __restrict__ row,
                                         int* cx, int* cy, int* cz) {
    float x = row[0], y = row[1], z = row[2];
    int gx = (int)floorf((x - MINX) / VOXX);
    int gy = (int)floorf((y - MINY) / VOXY);
    int gz = (int)floorf((z - MINZ) / VOXZ);
    gx = min(max(gx, 0), GXD - 1);
    gy = min(max(gy, 0), GYD - 1);
    gz = min(max(gz, 0), GZD - 1);
    *cx = gx; *cy = gy; *cz = gz;
    return (gx * GYD + gy) * GZD + gz;
}

// ===========================================================================
// FAST PATH — workspace (floats):
//   M0 : [0, GCELLS+64)                  cell counts; [GCELLS..] zero sentinel
//   MM : interleaved (m1,m2) per (cell,feature); elem GCELLS*128.. = zero row
// ===========================================================================

__global__ void lbki_zero_rows(const float* __restrict__ pc,
                               float2* __restrict__ MM2,
                               int npts) {
    int lane = threadIdx.x & 63;
    int wave = threadIdx.x >> 6;
    int p = blockIdx.x * (blockDim.x >> 6) + wave;
    if (p >= npts) return;
    int cx, cy, cz;
    int g = base_cell(pc + (size_t)p * 67, &cx, &cy, &cz);
    MM2[(size_t)g * DD + lane] = make_float2(0.0f, 0.0f);
}

__global__ void lbki_build(const float* __restrict__ pc,
                           float* __restrict__ M0,
                           float* __restrict__ MM,
                           int npts) {
    int lane = threadIdx.x & 63;
    int wave = threadIdx.x >> 6;
    int p = blockIdx.x * (blockDim.x >> 6) + wave;
    if (p >= npts) return;
    const float* row = pc + (size_t)p * 67;
    int cx, cy, cz;
    int g = base_cell(row, &cx, &cy, &cz);
    float f = row[3 + lane];
    size_t e = ((size_t)g * DD + lane) * 2;
    atomicAdd(&MM[e],     f);
    atomicAdd(&MM[e + 1], f * f);
    if (lane == 0) atomicAdd(&M0[g], 1.0f);
}

// z-column stencil fused with finalize. Block = 4 adjacent y-columns (one
// wave each, lane = feature). M0 halo staged in LDS; per-plane moments
// reduced to rolling scalars on arrival; partial unroll (4) keeps code tiny.
__global__ __launch_bounds__(256)
void lbki_stencil_col2(const float* __restrict__ M0,
                       const float* __restrict__ MM,
                       const float* __restrict__ mean_map,
                       const float* __restrict__ var_map,
                       const float* __restrict__ conf_map,
                       float* __restrict__ out_mean,
                       float* __restrict__ out_var,
                       float* __restrict__ out_conf,
                       KvCols ka) {
    __shared__ float sm0[3 * 6 * 34];   // [xo][yo][zp], z padded 32->34 (zeros)
    const int tid  = threadIdx.x;
    const int lane = tid & 63;
    const int wave = tid >> 6;

    // bijective XCD swizzle (4096 blocks, % 8 == 0)
    unsigned b = blockIdx.x;
    unsigned chunk = gridDim.x >> 3;
    unsigned swz = (b & 7u) * chunk + (b >> 3);
    const int col0 = (int)(swz * 4u);
    const int cx  = col0 >> 7;          // block's x (4 cols share it; 128%4==0)
    const int cy0 = col0 & 127;

    // ---- stage M0 halo into LDS (zeros outside grid / z pad) ----
    for (int e = tid; e < 3 * 6 * 34; e += 256) {
        int xo = e / 204;               // 204 = 6*34
        int r  = e - xo * 204;
        int yo = r / 34;
        int zp = r - yo * 34;
        int gx_ = cx - 1 + xo;
        int gy_ = cy0 - 1 + yo;
        bool v = ((unsigned)gx_ < (unsigned)GXD) &&
                 ((unsigned)gy_ < (unsigned)GYD) && (zp < GZD);
        float val = 0.0f;
        if (v) val = M0[((gx_ << 7) + gy_) * 32 + zp];
        sm0[e] = val;
    }
    __syncthreads();

    const int cy = cy0 + wave;
    const int wb = wave * 34;           // LDS y-row base for this wave

    // MM element index of tap c at plane z: baseElem + KC(c) + z*128
    // (value only used when gate is on => indices valid then; modular
    //  arithmetic makes the shared base safe even when b0 < 0)
    const int b0 = ((cx - 1) * GYD + (cy - 1)) * GZD;     // cell idx, may be <0
    const unsigned baseElem = (unsigned)b0 * 128u + (unsigned)lane * 2u;
    const unsigned sentM    = (unsigned)GCELLS * 128u + (unsigned)lane * 2u;

    const unsigned gbase = (unsigned)((cx << 7) + cy) * 32u;
    const unsigned rbase = gbase * 64u + (unsigned)lane;

    float Y0[4], Y1[4], S0[4], S1[4], q0[4], q1[4];
    float2 inf[9];

    // LDS offset constant per c (compile-time), MM offset constant per c
#define LDSC(c) ((((c) / 3) * 6 + ((c) % 3)) * 34)
#define KC(c)   ((unsigned)((((c) / 3) * GYD + ((c) % 3)) * GZD) * 128u)

    // ---- prologue: planes 0 and 1 ----
    {
        float c0[9], c1[9];
        #pragma unroll
        for (int c = 0; c < 9; ++c) c0[c] = sm0[wb + LDSC(c) + 0];
        #pragma unroll
        for (int c = 0; c < 9; ++c) c1[c] = sm0[wb + LDSC(c) + 1];
        float a00 = 0, a10 = 0, a01 = 0, a11 = 0;
        #pragma unroll
        for (int c = 0; c < 9; ++c) {
            a00 += ka.w0[c] * c0[c];
            a01 += ka.w0[c] * c1[c];
            if (IS_PLUS(c)) { a10 += ka.w1[c] * c0[c]; a11 += ka.w1[c] * c1[c]; }
        }
        q0[0] = a00; q1[0] = a10; q0[1] = a01; q1[1] = a11;

        // plane 0: issue + immediate reduce (one-time startup stall)
        #pragma unroll
        for (int c = 0; c < 9; ++c) {
            unsigned mi = (c0[c] != 0.0f) ? (baseElem + KC(c)) : sentM;
            inf[c] = *(const float2*)(MM + mi);
        }
        float y0 = 0, y1 = 0, s0 = 0, s1 = 0;
        #pragma unroll
        for (int c = 0; c < 9; ++c) {
            y0 += ka.w0[c] * inf[c].x; s0 += ka.w0[c] * inf[c].y;
            if (IS_PLUS(c)) { y1 += ka.w1[c] * inf[c].x; s1 += ka.w1[c] * inf[c].y; }
        }
        Y0[0] = y0; Y1[0] = y1; S0[0] = s0; S1[0] = s1;

        // plane 1: issue, leave in flight
        #pragma unroll
        for (int c = 0; c < 9; ++c) {
            unsigned mi = (c1[c] != 0.0f) ? (baseElem + KC(c) + 128u) : sentM;
            inf[c] = *(const float2*)(MM + mi);
        }
        Y0[3] = Y1[3] = S0[3] = S1[3] = 0.0f;   // plane -1
        q0[3] = q1[3] = 0.0f;
    }

    // ---- main loop: 8 outer iterations x 4-unrolled (static window slots) ----
    for (int zb = 0; zb < 8; ++zb) {
        #pragma unroll
        for (int k = 0; k < 4; ++k) {
            const int z = zb * 4 + k;
            const int sZ2 = (k + 2) & 3;    // plane z+2
            const int sZ1 = (k + 1) & 3;    // plane z+1
            const int sZ0 = k;              // plane z / cell z
            const int sZm = (k + 3) & 3;    // plane z-1

            // 1: LDS cnt for plane z+2 (z+2 <= 33 < 34 pad; zeros past 31)
            float cv[9];
            #pragma unroll
            for (int c = 0; c < 9; ++c) cv[c] = sm0[wb + LDSC(c) + (z + 2)];

            // 2: maps for cell z
            float mean = mean_map[rbase + (unsigned)z * 64u];
            float var  = var_map [rbase + (unsigned)z * 64u];
            float conf = conf_map[gbase + (unsigned)z];

            // 3: reduce plane z+1 (issued last iteration)
            float y0 = 0, y1 = 0, s0 = 0, s1 = 0;
            #pragma unroll
            for (int c = 0; c < 9; ++c) {
                y0 += ka.w0[c] * inf[c].x; s0 += ka.w0[c] * inf[c].y;
                if (IS_PLUS(c)) { y1 += ka.w1[c] * inf[c].x; s1 += ka.w1[c] * inf[c].y; }
            }
            Y0[sZ1] = y0; Y1[sZ1] = y1; S0[sZ1] = s0; S1[sZ1] = s1;

            // 4: q for plane z+2 + issue its MM loads (overwrites inf)
            float a0 = 0, a1 = 0;
            #pragma unroll
            for (int c = 0; c < 9; ++c) {
                a0 += ka.w0[c] * cv[c];
                if (IS_PLUS(c)) a1 += ka.w1[c] * cv[c];
            }
            q0[sZ2] = a0; q1[sZ2] = a1;
            #pragma unroll
            for (int c = 0; c < 9; ++c) {
                unsigned mi = (cv[c] != 0.0f)
                            ? (baseElem + KC(c) + (unsigned)(z + 2) * 128u)
                            : sentM;
                inf[c] = *(const float2*)(MM + mi);
            }

            // 5: finalize cell z
            float acc_k = q1[sZm] + q0[sZ0] + q1[sZ1];
            float acc_y = Y0[sZ0] + Y1[sZm] + Y1[sZ1];
            float acc_s = S0[sZ0] + S1[sZm] + S1[sZ1];
            float kb    = acc_k;
            float ybar  = acc_y / (kb + EPSV);
            float Sbar  = acc_s - 2.0f * ybar * acc_y + ybar * ybar * kb;
            float denom = conf + kb + EPSV;
            float dm    = ybar - mean;
            float scal  = conf * kb / denom;
            unsigned oi = rbase + (unsigned)z * 64u;
            out_mean[oi] = (conf * mean + kb * ybar) / denom;
            out_var[oi]  = var + Sbar + scal * dm * dm;
            if (lane == 0) out_conf[gbase + (unsigned)z] = conf + kb;
        }
    }
#undef LDSC
#undef KC
}

// ===========================================================================
// FALLBACK PATH (round-1 kernels, used only if workspace is too small)
// ===========================================================================
__global__ void lbki_accum(const float* __restrict__ pc,
                           float* __restrict__ y_sum,
                           float* __restrict__ sq_sum,
                           float* __restrict__ k_bar,
                           int npts) {
    __shared__ float kval_s[27];
    if (threadIdx.x < 27) kval_s[threadIdx.x] = kval_of(threadIdx.x);
    __syncthreads();

    int lane = threadIdx.x & 63;
    int wave = threadIdx.x >> 6;
    int p = blockIdx.x * (blockDim.x >> 6) + wave;
    if (p >= npts) return;

    const float* row = pc + (size_t)p * 67;
    int gx, gy, gz;
    base_cell(row, &gx, &gy, &gz);
    float f = row[3 + lane];
    float ff = f * f;

    #pragma unroll
    for (int o = 0; o < 27; ++o) {
        float kv = kval_s[o];
        if (kv <= 0.0f) continue;
        int nx = gx + (o / 9) - 1;
        int ny = gy + ((o / 3) % 3) - 1;
        int nz = gz + (o % 3) - 1;
        if ((unsigned)nx >= (unsigned)GXD) continue;
        if ((unsigned)ny >= (unsigned)GYD) continue;
        if ((unsigned)nz >= (unsigned)GZD) continue;
        size_t g = ((size_t)nx * GYD + ny) * GZD + nz;
        atomicAdd(&y_sum[g * DD + lane], kv * f);
        atomicAdd(&sq_sum[g * DD + lane], kv * ff);
        if (lane == 0) atomicAdd(&k_bar[g], kv);
    }
}

__global__ void lbki_finalize(const float* __restrict__ mean_map,
                              const float* __restrict__ var_map,
                              const float* __restrict__ conf_map,
                              float* __restrict__ out_mean,
                              float* __restrict__ out_var,
                              float* __restrict__ out_conf) {
    int lane = threadIdx.x & 63;
    int wave = threadIdx.x >> 6;
    int g = blockIdx.x * (blockDim.x >> 6) + wave;
    if (g >= GCELLS) return;

    float kb   = out_conf[g];
    float conf = conf_map[g];

    size_t idx = (size_t)g * DD + lane;
    float ys   = out_mean[idx];
    float sq   = out_var[idx];
    float mean = mean_map[idx];
    float var  = var_map[idx];

    float ybar  = ys / (kb + EPSV);
    float Sbar  = sq - 2.0f * ybar * ys + ybar * ybar * kb;
    float denom = conf + kb + EPSV;
    float dm    = ybar - mean;
    float scal  = conf * kb / denom;

    out_mean[idx] = (conf * mean + kb * ybar) / denom;
    out_var[idx]  = var + Sbar + scal * dm * dm;
    if (lane == 0) out_conf[g] = conf + kb;
}

// ===========================================================================
extern "C" void kernel_launch(void* const* d_in, const int* in_sizes, int n_in,
                              void* d_out, int out_size, void* d_ws, size_t ws_size,
                              hipStream_t stream) {
    const float* mean_map = (const float*)d_in[0];
    const float* var_map  = (const float*)d_in[1];
    const float* conf_map = (const float*)d_in[2];
    const float* pc       = (const float*)d_in[3];
    int npts = in_sizes[3] / 67;

    float* out      = (float*)d_out;
    float* out_mean = out;
    float* out_var  = out + (size_t)GCELLS * DD;
    float* out_conf = out + (size_t)2 * GCELLS * DD;

    const size_t M0_ELEMS = (size_t)GCELLS + 64;             // + sentinel
    const size_t MM_ELEMS = (size_t)GCELLS * DD * 2 + 128;   // + sentinel row
    const size_t WS_NEEDED = (M0_ELEMS + MM_ELEMS) * sizeof(float);

    if (ws_size >= WS_NEEDED) {
        float* M0 = (float*)d_ws;
        float* MM = M0 + M0_ELEMS;

        hipMemsetAsync(M0, 0, M0_ELEMS * sizeof(float), stream);
        hipMemsetAsync(MM + (size_t)GCELLS * DD * 2, 0, 128 * sizeof(float), stream);

        int wpb = 4;
        int pblocks = (npts + wpb - 1) / wpb;
        lbki_zero_rows<<<pblocks, 256, 0, stream>>>(pc, (float2*)MM, npts);
        lbki_build<<<pblocks, 256, 0, stream>>>(pc, M0, MM, npts);

        // host-side column weights (double precision, cast to f32)
        KvCols ka;
        for (int c = 0; c < 9; ++c) {
            int ox = c / 3 - 1, oy = c % 3 - 1;
            for (int k = 0; k < 2; ++k) {   // k = |oz|
                double dx = ox * (double)VOXX;
                double dy = oy * (double)VOXY;
                double dz = k  * (double)VOXZ;
                double d  = sqrt(dx * dx + dy * dy + dz * dz);
                double ang = 2.0 * (double)PIF * d / (double)ELL;
                double v = (1.0 / 3.0) * (2.0 + cos(ang)) * (1.0 - d / (double)ELL)
                         + (1.0 / (2.0 * (double)PIF)) * sin(ang);
                if (d >= (double)ELL) v = 0.0;
                v = v < 0.0 ? 0.0 : (v > 1.0 ? 1.0 : v);
                if (k == 0) ka.w0[c] = (float)v; else ka.w1[c] = (float)v;
            }
        }

        int sblocks = (GXD * GYD) / 4;   // 4096 blocks, % 8 == 0
        lbki_stencil_col2<<<sblocks, 256, 0, stream>>>(M0, MM,
                                                       mean_map, var_map, conf_map,
                                                       out_mean, out_var, out_conf,
                                                       ka);
    } else {
        hipMemsetAsync(d_out, 0, (size_t)out_size * sizeof(float), stream);
        int wpb = 4;
        int blocks = (npts + wpb - 1) / wpb;
        lbki_accum<<<blocks, 256, 0, stream>>>(pc, out_mean, out_var, out_conf, npts);
        int fblocks = GCELLS / 4;
        lbki_finalize<<<fblocks, 256, 0, stream>>>(mean_map, var_map, conf_map,
                                                   out_mean, out_var, out_conf);
    }
}